// Round 5
// baseline (279.261 us; speedup 1.0000x reference)
//
#include <hip/hip_runtime.h>
#include <hip/hip_bf16.h>
#include <stdint.h>

// ---------------- types ----------------
typedef short shortx8 __attribute__((ext_vector_type(8)));
typedef float floatx4 __attribute__((ext_vector_type(4)));

#define T_LEN 2048
#define BATCH 16
#define DMODEL 512
#define HDIM 512
#define M_ROWS (T_LEN * BATCH)          // 32768
#define NCHUNK 64
#define LCHUNK 32                        // T per chunk
#define NCHAIN (BATCH * HDIM)            // 8192
#define Y_ELEMS (M_ROWS * DMODEL)        // 16777216

// ---------------- helpers ----------------
__device__ __forceinline__ unsigned short f2bf(float f) {
    union { float f; unsigned u; } v; v.f = f;
    unsigned r = (v.u + 0x7FFFu + ((v.u >> 16) & 1u)) >> 16;
    return (unsigned short)r;
}
__device__ __forceinline__ float bf2f(unsigned short u) {
    union { unsigned u; float f; } v; v.u = ((unsigned)u) << 16;
    return v.f;
}
// packed fp32x2 -> bf16x2 (v_cvt_pk_bf16_f32 on gfx950); low 16 = a, high 16 = b
__device__ __forceinline__ unsigned pk2(float a, float b) {
    union { __hip_bfloat162 h; unsigned u; } v;
    v.h = __float22bfloat162_rn(make_float2(a, b));
    return v.u;
}

// ---------------- prep: per-channel Lam, Lam^32, gamma ----------------
__global__ void prep_kernel(const float* __restrict__ nu_log, const float* __restrict__ th_log,
                            float* lam_re, float* lam_im, float* l32_re, float* l32_im, float* gam) {
    int h = blockIdx.x * blockDim.x + threadIdx.x;
    if (h >= HDIM) return;
    double nu  = exp((double)nu_log[h]);
    double th  = exp((double)th_log[h]);
    double mag = exp(-nu);
    double lre = mag * cos(th), lim = mag * sin(th);
    double g   = sqrt(1.0 - exp(-2.0 * nu));
    double zr = lre, zi = lim;
    for (int i = 0; i < 5; ++i) { double nr = zr*zr - zi*zi; zi = 2.0*zr*zi; zr = nr; }  // lam^32
    lam_re[h] = (float)lre; lam_im[h] = (float)lim;
    l32_re[h] = (float)zr;  l32_im[h] = (float)zi;
    gam[h] = (float)g;
}

// ---------------- merged operand conversion (INTERLEAVED complex layout) ----------------
// Bs (1024 x 512): row 2h = B_re[h]*gam, row 2h+1 = B_im[h]*gam
// C2 (512 x 1024): col 2h = C_re[d][h], col 2h+1 = -C_im[d][h]
__global__ void conv_BC_kernel(const float* __restrict__ B_re, const float* __restrict__ B_im,
                               const float* __restrict__ gam,
                               const float* __restrict__ C_re, const float* __restrict__ C_im,
                               unsigned short* __restrict__ Bs, unsigned short* __restrict__ C2) {
    int idx = blockIdx.x * blockDim.x + threadIdx.x;     // 0 .. 1M-1
    if (idx < 524288) {
        int n = idx >> 9;        // /512
        int d = idx & 511;
        int h = n >> 1, pb = n & 1;
        float v = (pb ? B_im[h * DMODEL + d] : B_re[h * DMODEL + d]) * gam[h];
        Bs[idx] = f2bf(v);
    } else {
        int i2 = idx - 524288;
        int d = i2 >> 10;        // /1024
        int k = i2 & 1023;
        int h = k >> 1, pb = k & 1;
        float v = pb ? -C_im[d * HDIM + h] : C_re[d * HDIM + h];
        C2[i2] = f2bf(v);
    }
}

// ---------------- GEMM1: Bu = x(fp32) . Bs^T, out bf16 interleaved ----------------
// X: M x 512 fp32 row-major. Bs: 1024 x 512 bf16 row-major (NT).  Out bf16 M x 1024.
// A staged via dwordx4 loads + v_cvt_pk_bf16_f32 + swizzled ds_write_b128;
// B staged via async global_load_lds (16B) with the same XOR swizzle.
__global__ __launch_bounds__(256, 4) void gemm_xb(const float* __restrict__ X,
                                                  const unsigned short* __restrict__ Bmat,
                                                  unsigned short* __restrict__ Out) {
    const int K = 512, N = 1024, lgNB = 3;
    __shared__ unsigned short As[128 * 64];
    __shared__ unsigned short Bsh[128 * 64];
    const int L = blockIdx.x;
    const int xcd = L & 7;
    const int slot = L >> 3;
    const int bn = slot & ((1 << lgNB) - 1);
    const int bm = xcd * 32 + (slot >> lgNB);
    const int tid = threadIdx.x;
    const int wv = tid >> 6, lane = tid & 63;
    const int wr = wv >> 1, wc = wv & 1;
    const int lrow = lane & 15, qq = lane >> 4;
    floatx4 acc[4][4] = {};

    const size_t rowA = (size_t)bm * 128, rowB = (size_t)bn * 128;
    for (int k0 = 0; k0 < K; k0 += 64) {
        // B tile: async, LDS slot ch holds global 16B-chunk (ch&7)^(r&7) of row r
        #pragma unroll
        for (int j = 0; j < 4; ++j) {
            int ch  = j * 256 + wv * 64 + lane;
            int r   = ch >> 3;
            int c16 = ch & 7;
            int g16 = c16 ^ (r & 7);
            const unsigned short* gb = Bmat + (rowB + r) * (size_t)K + (k0 + g16 * 8);
            unsigned short* lb = Bsh + (size_t)(j * 256 + wv * 64) * 8;   // wave-uniform base
            __builtin_amdgcn_global_load_lds((const __attribute__((address_space(1))) void*)gb,
                                             (__attribute__((address_space(3))) void*)lb, 16, 0, 0);
        }
        // A tile: fp32 load -> packed cvt -> ds_write_b128 (same swizzle)
        #pragma unroll
        for (int j = 0; j < 4; ++j) {
            int ch  = j * 256 + tid;
            int r   = ch >> 3;
            int c16 = ch & 7;
            int g16 = c16 ^ (r & 7);
            const float* gx = X + (rowA + r) * (size_t)K + (k0 + g16 * 8);
            float4 a0 = *(const float4*)gx;
            float4 a1 = *(const float4*)(gx + 4);
            uint4 w;
            w.x = pk2(a0.x, a0.y); w.y = pk2(a0.z, a0.w);
            w.z = pk2(a1.x, a1.y); w.w = pk2(a1.z, a1.w);
            *(uint4*)&As[(size_t)ch * 8] = w;
        }
        __syncthreads();
        #pragma unroll
        for (int s = 0; s < 2; ++s) {
            shortx8 af[4], bf[4];
            #pragma unroll
            for (int mi = 0; mi < 4; ++mi) {
                int row = wr * 64 + mi * 16 + lrow;
                int c16 = (s * 4 + qq) ^ (row & 7);
                af[mi] = *(const shortx8*)&As[row * 64 + c16 * 8];
            }
            #pragma unroll
            for (int ni = 0; ni < 4; ++ni) {
                int row = wc * 64 + ni * 16 + lrow;
                int c16 = (s * 4 + qq) ^ (row & 7);
                bf[ni] = *(const shortx8*)&Bsh[row * 64 + c16 * 8];
            }
            #pragma unroll
            for (int mi = 0; mi < 4; ++mi)
                #pragma unroll
                for (int ni = 0; ni < 4; ++ni)
                    acc[mi][ni] = __builtin_amdgcn_mfma_f32_16x16x32_bf16(af[mi], bf[ni], acc[mi][ni], 0, 0, 0);
        }
        __syncthreads();
    }
    // epilogue: D row = qq*4 + r, col = lrow
    #pragma unroll
    for (int mi = 0; mi < 4; ++mi) {
        int mbase = bm * 128 + wr * 64 + mi * 16 + qq * 4;
        #pragma unroll
        for (int ni = 0; ni < 4; ++ni) {
            int n = bn * 128 + wc * 64 + ni * 16 + lrow;
            #pragma unroll
            for (int r = 0; r < 4; ++r)
                Out[(size_t)(mbase + r) * N + n] = f2bf(acc[mi][ni][r]);
        }
    }
}

// ---------------- GEMM2: y = h(bf16) . C2^T + Dv*x, out fp32 ----------------
__global__ __launch_bounds__(256, 4) void gemm_hc(const unsigned short* __restrict__ H2,
                                                  const unsigned short* __restrict__ C2,
                                                  const float* __restrict__ X,
                                                  const float* __restrict__ Dv,
                                                  float* __restrict__ Y) {
    const int K = 1024, N = 512, lgNB = 2;
    __shared__ unsigned short As[128 * 64];
    __shared__ unsigned short Bsh[128 * 64];
    const int L = blockIdx.x;
    const int xcd = L & 7;
    const int slot = L >> 3;
    const int bn = slot & ((1 << lgNB) - 1);
    const int bm = xcd * 32 + (slot >> lgNB);
    const int tid = threadIdx.x;
    const int wv = tid >> 6, lane = tid & 63;
    const int wr = wv >> 1, wc = wv & 1;
    const int lrow = lane & 15, qq = lane >> 4;
    floatx4 acc[4][4] = {};

    const size_t rowA = (size_t)bm * 128, rowB = (size_t)bn * 128;
    for (int k0 = 0; k0 < K; k0 += 64) {
        #pragma unroll
        for (int j = 0; j < 4; ++j) {
            int ch  = j * 256 + wv * 64 + lane;
            int r   = ch >> 3;
            int c16 = ch & 7;
            int g16 = c16 ^ (r & 7);
            const unsigned short* ga = H2 + (rowA + r) * (size_t)K + (k0 + g16 * 8);
            const unsigned short* gb = C2 + (rowB + r) * (size_t)K + (k0 + g16 * 8);
            unsigned short* la = As  + (size_t)(j * 256 + wv * 64) * 8;
            unsigned short* lb = Bsh + (size_t)(j * 256 + wv * 64) * 8;
            __builtin_amdgcn_global_load_lds((const __attribute__((address_space(1))) void*)ga,
                                             (__attribute__((address_space(3))) void*)la, 16, 0, 0);
            __builtin_amdgcn_global_load_lds((const __attribute__((address_space(1))) void*)gb,
                                             (__attribute__((address_space(3))) void*)lb, 16, 0, 0);
        }
        __syncthreads();
        #pragma unroll
        for (int s = 0; s < 2; ++s) {
            shortx8 af[4], bf[4];
            #pragma unroll
            for (int mi = 0; mi < 4; ++mi) {
                int row = wr * 64 + mi * 16 + lrow;
                int c16 = (s * 4 + qq) ^ (row & 7);
                af[mi] = *(const shortx8*)&As[row * 64 + c16 * 8];
            }
            #pragma unroll
            for (int ni = 0; ni < 4; ++ni) {
                int row = wc * 64 + ni * 16 + lrow;
                int c16 = (s * 4 + qq) ^ (row & 7);
                bf[ni] = *(const shortx8*)&Bsh[row * 64 + c16 * 8];
            }
            #pragma unroll
            for (int mi = 0; mi < 4; ++mi)
                #pragma unroll
                for (int ni = 0; ni < 4; ++ni)
                    acc[mi][ni] = __builtin_amdgcn_mfma_f32_16x16x32_bf16(af[mi], bf[ni], acc[mi][ni], 0, 0, 0);
        }
        __syncthreads();
    }
    #pragma unroll
    for (int mi = 0; mi < 4; ++mi) {
        int mbase = bm * 128 + wr * 64 + mi * 16 + qq * 4;
        #pragma unroll
        for (int ni = 0; ni < 4; ++ni) {
            int n = bn * 128 + wc * 64 + ni * 16 + lrow;
            float dv = Dv[n];
            #pragma unroll
            for (int r = 0; r < 4; ++r) {
                size_t idx = (size_t)(mbase + r) * N + n;
                Y[idx] = acc[mi][ni][r] + dv * X[idx];
            }
        }
    }
}

// ---------------- scan pass 1: per-chunk partial, 4 channels/thread, 16B loads -----
__global__ void scan_partial(const unsigned short* __restrict__ Bu,
                             const float* __restrict__ lam_re, const float* __restrict__ lam_im,
                             float* __restrict__ car) {
    int gid = blockIdx.x * blockDim.x + threadIdx.x;     // 0 .. 131071
    int chunk = gid >> 11;
    int idx = gid & 2047;
    int b = idx >> 7, q = idx & 127;
    int h = q * 4;
    float4 lr4 = *(const float4*)&lam_re[h];
    float4 li4 = *(const float4*)&lam_im[h];
    float lrr[4] = {lr4.x, lr4.y, lr4.z, lr4.w};
    float lii[4] = {li4.x, li4.y, li4.z, li4.w};
    float vr[4] = {0.f, 0.f, 0.f, 0.f}, vi[4] = {0.f, 0.f, 0.f, 0.f};
    const unsigned short* p = Bu + (size_t)(chunk * LCHUNK * BATCH + b) * 1024 + q * 8;
    for (int j = 0; j < LCHUNK; ++j) {
        uint4 w = *(const uint4*)p;
        unsigned wsv[4] = {w.x, w.y, w.z, w.w};
        #pragma unroll
        for (int c = 0; c < 4; ++c) {
            float br = bf2f((unsigned short)wsv[c]);
            float bi = bf2f((unsigned short)(wsv[c] >> 16));
            float nr = lrr[c] * vr[c] - lii[c] * vi[c] + br;
            float ni = lrr[c] * vi[c] + lii[c] * vr[c] + bi;
            vr[c] = nr; vi[c] = ni;
        }
        p += BATCH * 1024;
    }
    float* cp = car + (size_t)(chunk * 2048 + idx) * 8;
    *(float4*)cp       = make_float4(vr[0], vi[0], vr[1], vi[1]);
    *(float4*)(cp + 4) = make_float4(vr[2], vi[2], vr[3], vi[3]);
}

// ---------------- scan pass 2 (fused prefix+apply), in-place h over Bu ----------------
__global__ void scan_apply(unsigned short* __restrict__ Bu,
                           const float* __restrict__ lam_re, const float* __restrict__ lam_im,
                           const float* __restrict__ l32_re, const float* __restrict__ l32_im,
                           const float* __restrict__ h0_re, const float* __restrict__ h0_im,
                           const float* __restrict__ car,
                           float* __restrict__ out_final, int interleave) {
    int gid = blockIdx.x * blockDim.x + threadIdx.x;
    int chunk = gid >> 11;           // block-uniform (2048 threads = 8 blocks per chunk)
    int idx = gid & 2047;
    int b = idx >> 7, q = idx & 127;
    int h = q * 4;
    int c0 = b * 512 + h;
    // carry-in: h0 advanced through preceding chunks via lam^32
    float4 Lr4 = *(const float4*)&l32_re[h];
    float4 Li4 = *(const float4*)&l32_im[h];
    float Lr[4] = {Lr4.x, Lr4.y, Lr4.z, Lr4.w};
    float Li[4] = {Li4.x, Li4.y, Li4.z, Li4.w};
    float4 h0r = *(const float4*)&h0_re[c0];
    float4 h0i = *(const float4*)&h0_im[c0];
    float vr[4] = {h0r.x, h0r.y, h0r.z, h0r.w};
    float vi[4] = {h0i.x, h0i.y, h0i.z, h0i.w};
    for (int k = 0; k < chunk; ++k) {
        const float* cp = car + (size_t)(k * 2048 + idx) * 8;
        float4 a = *(const float4*)cp;        // r0,i0,r1,i1
        float4 bq = *(const float4*)(cp + 4); // r2,i2,r3,i3
        float cr[4] = {a.x, a.z, bq.x, bq.z};
        float ci[4] = {a.y, a.w, bq.y, bq.w};
        #pragma unroll
        for (int c = 0; c < 4; ++c) {
            float nr = Lr[c] * vr[c] - Li[c] * vi[c] + cr[c];
            float ni = Lr[c] * vi[c] + Li[c] * vr[c] + ci[c];
            vr[c] = nr; vi[c] = ni;
        }
    }
    // main streaming recurrence
    float4 lr4 = *(const float4*)&lam_re[h];
    float4 li4 = *(const float4*)&lam_im[h];
    float lrr[4] = {lr4.x, lr4.y, lr4.z, lr4.w};
    float lii[4] = {li4.x, li4.y, li4.z, li4.w};
    unsigned short* p = Bu + (size_t)(chunk * LCHUNK * BATCH + b) * 1024 + q * 8;
    for (int j = 0; j < LCHUNK; ++j) {
        uint4 w = *(const uint4*)p;
        unsigned wsv[4] = {w.x, w.y, w.z, w.w};
        #pragma unroll
        for (int c = 0; c < 4; ++c) {
            float br = bf2f((unsigned short)wsv[c]);
            float bi = bf2f((unsigned short)(wsv[c] >> 16));
            float nr = lrr[c] * vr[c] - lii[c] * vi[c] + br;
            float ni = lrr[c] * vi[c] + lii[c] * vr[c] + bi;
            vr[c] = nr; vi[c] = ni;
        }
        uint4 o;
        o.x = (unsigned)f2bf(vr[0]) | ((unsigned)f2bf(vi[0]) << 16);
        o.y = (unsigned)f2bf(vr[1]) | ((unsigned)f2bf(vi[1]) << 16);
        o.z = (unsigned)f2bf(vr[2]) | ((unsigned)f2bf(vi[2]) << 16);
        o.w = (unsigned)f2bf(vr[3]) | ((unsigned)f2bf(vi[3]) << 16);
        *(uint4*)p = o;
        p += BATCH * 1024;
    }
    if (chunk == NCHUNK - 1) {       // final_state = h[T-1]
        if (interleave) {
            float* o = out_final + (size_t)c0 * 2;
            *(float4*)o       = make_float4(vr[0], vi[0], vr[1], vi[1]);
            *(float4*)(o + 4) = make_float4(vr[2], vi[2], vr[3], vi[3]);
        } else {
            *(float4*)&out_final[c0] = make_float4(vr[0], vr[1], vr[2], vr[3]);
        }
    }
}

// ---------------- launch ----------------
extern "C" void kernel_launch(void* const* d_in, const int* in_sizes, int n_in,
                              void* d_out, int out_size, void* d_ws, size_t ws_size,
                              hipStream_t stream) {
    const float* x        = (const float*)d_in[0];
    const float* h0_re    = (const float*)d_in[1];
    const float* h0_im    = (const float*)d_in[2];
    const float* nu_log   = (const float*)d_in[3];
    const float* theta_lg = (const float*)d_in[4];
    const float* B_re     = (const float*)d_in[5];
    const float* B_im     = (const float*)d_in[6];
    const float* C_re     = (const float*)d_in[7];
    const float* C_im     = (const float*)d_in[8];
    const float* D_vec    = (const float*)d_in[9];

    // workspace layout (~74 MB total)
    char* ws = (char*)d_ws;
    unsigned short* BuH  = (unsigned short*)(ws + 0);              // 64 MB (M x 1024 bf16, interleaved): Bu, then h
    unsigned short* Bs   = (unsigned short*)(ws + 67108864);       // 1 MB  (1024 x 512 bf16)
    unsigned short* C2   = (unsigned short*)(ws + 68157440);       // 1 MB  (512 x 1024 bf16)
    float* car           = (float*)(ws + 69206016);                // 4 MB  (64 x 2048 x 8 fp32)
    float* lam_re        = (float*)(ws + 73400320);
    float* lam_im        = (float*)(ws + 73402368);
    float* l32_re        = (float*)(ws + 73404416);
    float* l32_im        = (float*)(ws + 73406464);
    float* gam           = (float*)(ws + 73408512);

    // adaptive d_out layout: out_size = Y_ELEMS + {16384 interleaved | 8192 real-only}
    int fs_elems = out_size - Y_ELEMS;
    int interleave = (fs_elems == 8192) ? 0 : 1;
    if (fs_elems != 8192) fs_elems = 16384;
    float* out_final = (float*)d_out;
    float* y_out     = (float*)d_out + fs_elems;

    // 1. channel constants
    prep_kernel<<<2, 256, 0, stream>>>(nu_log, theta_lg, lam_re, lam_im, l32_re, l32_im, gam);
    // 2. operand conversions (interleaved complex layout)
    conv_BC_kernel<<<4096, 256, 0, stream>>>(B_re, B_im, gam, C_re, C_im, Bs, C2);
    // 3. GEMM1: Bu = x (fp32, M x 512) . Bs^T -> M x 1024 bf16 (interleaved)
    gemm_xb<<<2048, 256, 0, stream>>>(x, Bs, BuH);
    // 4. chunked scan over T (partial -> fused prefix+apply, h overwrites Bu in-place)
    scan_partial<<<512, 256, 0, stream>>>(BuH, lam_re, lam_im, car);
    scan_apply<<<512, 256, 0, stream>>>(BuH, lam_re, lam_im, l32_re, l32_im,
                                        h0_re, h0_im, car, out_final, interleave);
    // 5. GEMM2: y = h (M x 1024) . C2^T + Dv*x -> M x 512 fp32
    gemm_hc<<<1024, 256, 0, stream>>>(BuH, C2, x, D_vec, y_out);
}